// Round 6
// baseline (638.149 us; speedup 1.0000x reference)
//
#include <hip/hip_runtime.h>

#define DEV __device__ __forceinline__

constexpr int NN = 50000;   // nodes
constexpr int NE = 400000;  // edges
constexpr int NG = 32;      // graphs
constexpr float EPSV = 1e-5f;
constexpr int SCAN_BLOCKS = 196;  // 196*256 = 50176 >= NN
constexpr int NSHARD = 8;         // stats shards (atomic-contention relief)
constexpr int STB = NSHARD * 128; // floats per BN-stats instance

constexpr int ECB = 2048;               // edge_combine blocks
constexpr int ESLOT = ECB * 256 / 8;    // 65536 edge slots

typedef __attribute__((ext_vector_type(8))) short s16x8;
typedef __attribute__((ext_vector_type(4))) float f32x4;

DEV unsigned short f2b(float f) {  // fp32 -> bf16 RNE (finite inputs)
  union { float f; unsigned u; } x; x.f = f;
  unsigned r = x.u + 0x7fffu + ((x.u >> 16) & 1u);
  return (unsigned short)(r >> 16);
}
DEV float b2f(unsigned short u) {
  union { unsigned u; float f; } x; x.u = ((unsigned)u) << 16; return x.f;
}

DEV s16x8 frag_from_f32(const float* p) {
  const float4 v0 = *(const float4*)p;
  const float4 v1 = *(const float4*)(p + 4);
  s16x8 af;
  af[0] = (short)f2b(v0.x); af[1] = (short)f2b(v0.y);
  af[2] = (short)f2b(v0.z); af[3] = (short)f2b(v0.w);
  af[4] = (short)f2b(v1.x); af[5] = (short)f2b(v1.y);
  af[6] = (short)f2b(v1.z); af[7] = (short)f2b(v1.w);
  return af;
}

DEV void ld8(float* d, const float* p) {
  float4 a = *(const float4*)p;
  float4 b = *(const float4*)(p + 4);
  d[0] = a.x; d[1] = a.y; d[2] = a.z; d[3] = a.w;
  d[4] = b.x; d[5] = b.y; d[6] = b.z; d[7] = b.w;
}

// sum the NSHARD shards of a stats instance and produce scale/shift for ch c.
DEV void bn_coeff(const float* __restrict__ st, const float* __restrict__ g,
                  const float* __restrict__ be, float invM, int c,
                  float& sc, float& sh) {
  float s = 0.f, s2 = 0.f;
#pragma unroll
  for (int k = 0; k < NSHARD; ++k) {
    s += st[k * 128 + c];
    s2 += st[k * 128 + 64 + c];
  }
  float mean = s * invM;
  float var = s2 * invM - mean * mean;
  sc = g[c] * rsqrtf(var + EPSV);
  sh = be[c] - mean * sc;
}

// ---------------------------------------------------------------------------
// hist + lin_in merged (independent work, one dispatch)
// ---------------------------------------------------------------------------
__global__ __launch_bounds__(256) void hist_lin_kernel(
    const int* __restrict__ dstI, int* __restrict__ deg,
    const float* __restrict__ x, const float* __restrict__ W,
    const float* __restrict__ b, float* __restrict__ h)
{
  int gid = blockIdx.x * 256 + threadIdx.x;
  if (gid < NE) atomicAdd(&deg[dstI[gid]], 1);
  if (gid < NN * 64) {
    int n = gid >> 6, c = gid & 63;
    float acc = b[c];
#pragma unroll
    for (int k = 0; k < 11; ++k)
      acc = fmaf(x[n * 11 + k], W[k * 64 + c], acc);
    h[gid] = acc;
  }
}

// ---------------------------------------------------------------------------
// CSR build: scan_pass1 -> scan_pass3 (pass2 folded in) -> fill_pos -> permute
// ---------------------------------------------------------------------------
__global__ __launch_bounds__(256) void scan_pass1(
    const int* __restrict__ deg, int* __restrict__ blockSums)
{
  __shared__ int red[4];
  int tid = threadIdx.x;
  int idx = blockIdx.x * 256 + tid;
  int v = (idx < NN) ? deg[idx] : 0;
#pragma unroll
  for (int off = 32; off > 0; off >>= 1) v += __shfl_down(v, off, 64);
  if ((tid & 63) == 0) red[tid >> 6] = v;
  __syncthreads();
  if (tid == 0) blockSums[blockIdx.x] = red[0] + red[1] + red[2] + red[3];
}

__global__ __launch_bounds__(256) void scan_pass3(
    const int* __restrict__ deg, const int* __restrict__ blockSums,
    int* __restrict__ rowptr, int* __restrict__ cursor)
{
  __shared__ int part[256];
  __shared__ int bsum[256];
  int tid = threadIdx.x;

  // redundant per-block scan of the 196 block sums (replaces scan_pass2)
  bsum[tid] = (tid < SCAN_BLOCKS) ? blockSums[tid] : 0;
  __syncthreads();
  for (int off = 1; off < 256; off <<= 1) {
    int t = 0;
    if (tid >= off) t = bsum[tid - off];
    __syncthreads();
    if (tid >= off) bsum[tid] += t;
    __syncthreads();
  }
  int blockOff = (blockIdx.x == 0) ? 0 : bsum[blockIdx.x - 1];

  int idx = blockIdx.x * 256 + tid;
  int v = (idx < NN) ? deg[idx] : 0;
  part[tid] = v;
  __syncthreads();
  for (int off = 1; off < 256; off <<= 1) {
    int t = 0;
    if (tid >= off) t = part[tid - off];
    __syncthreads();
    if (tid >= off) part[tid] += t;
    __syncthreads();
  }
  int excl = (tid == 0) ? 0 : part[tid - 1];
  int val = blockOff + excl;
  if (idx < NN) { rowptr[idx] = val; cursor[idx] = val; }
  if (idx == 0) rowptr[NN] = NE;
}

__global__ __launch_bounds__(256) void fill_pos_kernel(
    const int* __restrict__ dstI, int* __restrict__ cursor,
    int* __restrict__ eid)
{
  int e = blockIdx.x * 256 + threadIdx.x;
  if (e < NE) {
    int pos = atomicAdd(&cursor[dstI[e]], 1);
    eid[pos] = e;
  }
}

__global__ __launch_bounds__(256) void permute_kernel(
    const int* __restrict__ eid, const int* __restrict__ srcI,
    const int* __restrict__ dstI, const float* __restrict__ ea,
    int* __restrict__ srcP, int* __restrict__ dstP,
    float* __restrict__ eaP)
{
  int p = blockIdx.x * 256 + threadIdx.x;
  if (p < NE) {
    int e = eid[p];
    srcP[p] = srcI[e];
    dstP[p] = dstI[e];
    *(float4*)&eaP[(size_t)p * 4] = *(const float4*)&ea[(size_t)e * 4];
  }
}

// ---------------------------------------------------------------------------
// gemm_dual_mfma: Hd = hn @ W[0:64], Hs = hn @ W[64:128] (bf16 out, MFMA)
// where hn = (u2 ? h + relu(bn(u2)) : h) — fused residual of PREVIOUS layer;
// hn is written back to h (fp32) for aggr_concat / pool.
// ---------------------------------------------------------------------------
__global__ __launch_bounds__(256) void gemm_dual_mfma(
    float* __restrict__ h, const float* __restrict__ W, // 132x64
    const unsigned short* __restrict__ u2,              // may be null (layer 0)
    const float* __restrict__ st, const float* __restrict__ g,
    const float* __restrict__ be, float invM,
    unsigned short* __restrict__ Hd, unsigned short* __restrict__ Hs)
{
  __shared__ __align__(16) unsigned short Wt_s[2 * 64 * 72];  // [half][n][k]
  __shared__ float sc_s[64], sh_s[64];

  const int tid = threadIdx.x;
  const int lane = tid & 63;
  const int wave = tid >> 6;
  const int nn = lane & 15;
  const int kq = lane >> 4;

  if (u2 != nullptr && tid < 64) {
    float sc, sh;
    bn_coeff(st, g, be, invM, tid, sc, sh);
    sc_s[tid] = sc;
    sh_s[tid] = sh;
  }
#pragma unroll
  for (int i = 0; i < 32; ++i) {
    int idx = i * 256 + tid;          // 8192 = 2*64*64
    int half = idx >> 12;
    int rem = idx & 4095;
    int k = rem >> 6, n = rem & 63;
    Wt_s[half * 4608 + n * 72 + k] = f2b(W[idx]);
  }
  __syncthreads();

  s16x8 bfrag[2][4][2];  // [out][nt][kc]
#pragma unroll
  for (int o = 0; o < 2; ++o)
#pragma unroll
    for (int nt = 0; nt < 4; ++nt)
#pragma unroll
      for (int kc = 0; kc < 2; ++kc) {
        const unsigned short* p =
            &Wt_s[o * 4608 + (nt * 16 + nn) * 72 + kc * 32 + kq * 8];
#pragma unroll
        for (int j = 0; j < 8; ++j) bfrag[o][nt][kc][j] = (short)p[j];
      }

  const int rbase = blockIdx.x * 128 + wave * 32;

  f32x4 acc[2][2][4];  // [out][rt][nt]
#pragma unroll
  for (int o = 0; o < 2; ++o)
#pragma unroll
    for (int rt = 0; rt < 2; ++rt)
#pragma unroll
      for (int nt = 0; nt < 4; ++nt) acc[o][rt][nt] = (f32x4){0.f, 0.f, 0.f, 0.f};

#pragma unroll
  for (int rt = 0; rt < 2; ++rt) {
    int row = rbase + rt * 16 + nn;
    int rowc = row < NN ? row : NN - 1;
#pragma unroll
    for (int kc = 0; kc < 2; ++kc) {
      const int c0k = kc * 32 + kq * 8;
      s16x8 af;
      if (u2 != nullptr) {
        float* hp = &h[(size_t)rowc * 64 + c0k];
        float hv[8];
        ld8(hv, hp);
        uint4 uv = *(const uint4*)&u2[(size_t)rowc * 64 + c0k];
        const unsigned uw[4] = {uv.x, uv.y, uv.z, uv.w};
#pragma unroll
        for (int d = 0; d < 4; ++d) {
          union { unsigned u; float f; } lo, hi;
          lo.u = (uw[d] & 0xffffu) << 16;
          hi.u = uw[d] & 0xffff0000u;
          int j0 = d * 2, j1 = d * 2 + 1;
          hv[j0] += fmaxf(fmaf(sc_s[c0k + j0], lo.f, sh_s[c0k + j0]), 0.f);
          hv[j1] += fmaxf(fmaf(sc_s[c0k + j1], hi.f, sh_s[c0k + j1]), 0.f);
        }
        if (row < NN) {
          *(float4*)hp = make_float4(hv[0], hv[1], hv[2], hv[3]);
          *(float4*)(hp + 4) = make_float4(hv[4], hv[5], hv[6], hv[7]);
        }
#pragma unroll
        for (int j = 0; j < 8; ++j) af[j] = (short)f2b(hv[j]);
      } else {
        af = frag_from_f32(&h[(size_t)rowc * 64 + c0k]);
      }
#pragma unroll
      for (int o = 0; o < 2; ++o)
#pragma unroll
        for (int nt = 0; nt < 4; ++nt)
          acc[o][rt][nt] = __builtin_amdgcn_mfma_f32_16x16x32_bf16(
              af, bfrag[o][nt][kc], acc[o][rt][nt], 0, 0, 0);
    }
  }

#pragma unroll
  for (int rt = 0; rt < 2; ++rt)
#pragma unroll
    for (int nt = 0; nt < 4; ++nt) {
      int col = nt * 16 + nn;
#pragma unroll
      for (int reg = 0; reg < 4; ++reg) {
        int row = rbase + rt * 16 + kq * 4 + reg;
        if (row < NN) {
          Hd[(size_t)row * 64 + col] = f2b(acc[0][rt][nt][reg]);
          Hs[(size_t)row * 64 + col] = f2b(acc[1][rt][nt][reg]);
        }
      }
    }
}

// ---------------------------------------------------------------------------
// edge_combine: t1[p] = Hd[dstP[p]] + Hs[srcP[p]] + eaP[p]@Wb + b (bf16 out)
// + stats(st0). 8 lanes/edge, fully-unrolled dual-batch pipeline (R5).
// ---------------------------------------------------------------------------
__global__ __launch_bounds__(256) void edge_combine(
    const unsigned short* __restrict__ Hd, const unsigned short* __restrict__ Hs,
    const float* __restrict__ eaP, const int* __restrict__ srcP,
    const int* __restrict__ dstP, const float* __restrict__ Wb, // 4x64
    const float* __restrict__ bias, unsigned short* __restrict__ t1,
    float* __restrict__ outStats)
{
  __shared__ float red_s[128];
  const int tid = threadIdx.x;
  const int c0 = (tid & 7) * 8;
  float bv[8], w0[8], w1[8], w2[8], w3[8];
#pragma unroll
  for (int j = 0; j < 8; ++j) {
    bv[j] = bias[c0 + j];
    w0[j] = Wb[0 * 64 + c0 + j];
    w1[j] = Wb[1 * 64 + c0 + j];
    w2[j] = Wb[2 * 64 + c0 + j];
    w3[j] = Wb[3 * 64 + c0 + j];
  }

  float s[8], s2[8];
#pragma unroll
  for (int j = 0; j < 8; ++j) { s[j] = 0.f; s2[j] = 0.f; }

  const int e0 = (blockIdx.x * 256 + tid) >> 3;  // [0, ESLOT)

  // ---- batch A loads (unconditional) ----
  int eiA[4];
  float4 avA[4];
  uint4 hdA[4], hsA[4];
#pragma unroll
  for (int u = 0; u < 4; ++u) {
    int ec = e0 + u * ESLOT;
    eiA[u] = ec;
    int si = srcP[ec], di = dstP[ec];
    avA[u] = *(const float4*)&eaP[(size_t)ec * 4];
    hdA[u] = *(const uint4*)&Hd[(size_t)di * 64 + c0];
    hsA[u] = *(const uint4*)&Hs[(size_t)si * 64 + c0];
  }

  // ---- batch B loads (masked; invalid lanes clamp to e0, cache-hot) ----
  int eiB[3];
  bool hasB[3];
  float4 avB[3];
  uint4 hdB[3], hsB[3];
#pragma unroll
  for (int u = 0; u < 3; ++u) {
    int ee = e0 + (4 + u) * ESLOT;
    hasB[u] = ee < NE;
    int ec = hasB[u] ? ee : e0;
    eiB[u] = ec;
    int si = srcP[ec], di = dstP[ec];
    avB[u] = *(const float4*)&eaP[(size_t)ec * 4];
    hdB[u] = *(const uint4*)&Hd[(size_t)di * 64 + c0];
    hsB[u] = *(const uint4*)&Hs[(size_t)si * 64 + c0];
  }

  // ---- batch A compute + store ----
#pragma unroll
  for (int u = 0; u < 4; ++u) {
    const unsigned hdw[4] = {hdA[u].x, hdA[u].y, hdA[u].z, hdA[u].w};
    const unsigned hsw[4] = {hsA[u].x, hsA[u].y, hsA[u].z, hsA[u].w};
    const float4 av = avA[u];
    unsigned short ob[8];
#pragma unroll
    for (int d = 0; d < 4; ++d) {
      union { unsigned uu; float f; } a0, a1, b0, b1u;
      a0.uu = (hdw[d] & 0xffffu) << 16; a1.uu = hdw[d] & 0xffff0000u;
      b0.uu = (hsw[d] & 0xffffu) << 16; b1u.uu = hsw[d] & 0xffff0000u;
      int j0 = d * 2, j1 = d * 2 + 1;
      float y0 = a0.f + b0.f + bv[j0] + av.x * w0[j0] + av.y * w1[j0] + av.z * w2[j0] + av.w * w3[j0];
      float y1 = a1.f + b1u.f + bv[j1] + av.x * w0[j1] + av.y * w1[j1] + av.z * w2[j1] + av.w * w3[j1];
      ob[j0] = f2b(y0); ob[j1] = f2b(y1);
      s[j0] += y0; s2[j0] += y0 * y0;
      s[j1] += y1; s2[j1] += y1 * y1;
    }
    *(uint4*)&t1[(size_t)eiA[u] * 64 + c0] = *(const uint4*)ob;
  }

  // ---- batch B compute + store (masked) ----
#pragma unroll
  for (int u = 0; u < 3; ++u) {
    if (!hasB[u]) continue;
    const unsigned hdw[4] = {hdB[u].x, hdB[u].y, hdB[u].z, hdB[u].w};
    const unsigned hsw[4] = {hsB[u].x, hsB[u].y, hsB[u].z, hsB[u].w};
    const float4 av = avB[u];
    unsigned short ob[8];
#pragma unroll
    for (int d = 0; d < 4; ++d) {
      union { unsigned uu; float f; } a0, a1, b0, b1u;
      a0.uu = (hdw[d] & 0xffffu) << 16; a1.uu = hdw[d] & 0xffff0000u;
      b0.uu = (hsw[d] & 0xffffu) << 16; b1u.uu = hsw[d] & 0xffff0000u;
      int j0 = d * 2, j1 = d * 2 + 1;
      float y0 = a0.f + b0.f + bv[j0] + av.x * w0[j0] + av.y * w1[j0] + av.z * w2[j0] + av.w * w3[j0];
      float y1 = a1.f + b1u.f + bv[j1] + av.x * w0[j1] + av.y * w1[j1] + av.z * w2[j1] + av.w * w3[j1];
      ob[j0] = f2b(y0); ob[j1] = f2b(y1);
      s[j0] += y0; s2[j0] += y0 * y0;
      s[j1] += y1; s2[j1] += y1 * y1;
    }
    *(uint4*)&t1[(size_t)eiB[u] * 64 + c0] = *(const uint4*)ob;
  }

#pragma unroll
  for (int j = 0; j < 8; ++j) {
    s[j] += __shfl_xor(s[j], 8, 64);
    s[j] += __shfl_xor(s[j], 16, 64);
    s[j] += __shfl_xor(s[j], 32, 64);
    s2[j] += __shfl_xor(s2[j], 8, 64);
    s2[j] += __shfl_xor(s2[j], 16, 64);
    s2[j] += __shfl_xor(s2[j], 32, 64);
  }
  if (tid < 128) red_s[tid] = 0.f;
  __syncthreads();
  if ((tid & 63) < 8) {
#pragma unroll
    for (int j = 0; j < 8; ++j) {
      atomicAdd(&red_s[c0 + j], s[j]);
      atomicAdd(&red_s[64 + c0 + j], s2[j]);
    }
  }
  __syncthreads();
  if (tid < 128)
    atomicAdd(&outStats[(blockIdx.x & (NSHARD - 1)) * 128 + tid], red_s[tid]);
}

// ---------------------------------------------------------------------------
// gemm64_bn_mfma: out = relu(bn(A)) @ W + b — bf16 in/out, MFMA, in-place ok.
// 512-row block, 2 chunks of 64 rows per wave.
// ---------------------------------------------------------------------------
__global__ __launch_bounds__(256) void gemm64_bn_mfma(
    const unsigned short* A0,         // bf16 M x 64 (may alias outp)
    const float* __restrict__ W,      // 64 x 64 fp32
    const float* __restrict__ bias,
    const float* __restrict__ inStats,
    const float* __restrict__ inG,
    const float* __restrict__ inBe,
    float invM_in,
    unsigned short* outp,             // bf16 M x 64
    float* __restrict__ outStats,
    int M)
{
  __shared__ __align__(16) unsigned short Wt_s[64 * 72];
  __shared__ float scale_s[64];
  __shared__ float shift_s[64];
  __shared__ float red_s[128];

  const int tid = threadIdx.x;
  const int lane = tid & 63;
  const int wave = tid >> 6;
  const int nn = lane & 15;
  const int kq = lane >> 4;

  if (tid < 64) {
    float sc, sh;
    bn_coeff(inStats, inG, inBe, invM_in, tid, sc, sh);
    scale_s[tid] = sc;
    shift_s[tid] = sh;
  }
#pragma unroll
  for (int i = 0; i < 16; ++i) {
    int idx = i * 256 + tid;
    int k = idx >> 6, n = idx & 63;
    Wt_s[n * 72 + k] = f2b(W[idx]);
  }
  __syncthreads();

  s16x8 bfrag[4][2];
#pragma unroll
  for (int nt = 0; nt < 4; ++nt)
#pragma unroll
    for (int kc = 0; kc < 2; ++kc)
      bfrag[nt][kc] = *(const s16x8*)&Wt_s[(nt * 16 + nn) * 72 + kc * 32 + kq * 8];

  float scf[2][8], shf[2][8];
#pragma unroll
  for (int kc = 0; kc < 2; ++kc) {
    int k0 = kc * 32 + kq * 8;
    ld8(scf[kc], &scale_s[k0]);
    ld8(shf[kc], &shift_s[k0]);
  }

  float bcol[4];
#pragma unroll
  for (int nt = 0; nt < 4; ++nt) bcol[nt] = bias[nt * 16 + nn];

  float s[4] = {0.f, 0.f, 0.f, 0.f};
  float s2[4] = {0.f, 0.f, 0.f, 0.f};

  uint4 raw[4][2];
  f32x4 acc[4][4];

  // ---- chunk 0 loads ----
  const int rb0 = blockIdx.x * 512 + wave * 64;
#pragma unroll
  for (int rt = 0; rt < 4; ++rt) {
    int row = rb0 + rt * 16 + nn;
    int rowc = row < M ? row : M - 1;
#pragma unroll
    for (int kc = 0; kc < 2; ++kc)
      raw[rt][kc] = *(const uint4*)&A0[(size_t)rowc * 64 + kc * 32 + kq * 8];
  }

  // ---- chunk 0 compute ----
#pragma unroll
  for (int rt = 0; rt < 4; ++rt)
#pragma unroll
    for (int nt = 0; nt < 4; ++nt) acc[rt][nt] = (f32x4){0.f, 0.f, 0.f, 0.f};
#pragma unroll
  for (int rt = 0; rt < 4; ++rt) {
#pragma unroll
    for (int kc = 0; kc < 2; ++kc) {
      unsigned wbits[4] = {raw[rt][kc].x, raw[rt][kc].y, raw[rt][kc].z, raw[rt][kc].w};
      s16x8 af;
#pragma unroll
      for (int d = 0; d < 4; ++d) {
        union { unsigned u; float f; } lo, hi;
        lo.u = (wbits[d] & 0xffffu) << 16;
        hi.u = wbits[d] & 0xffff0000u;
        int j0 = d * 2, j1 = d * 2 + 1;
        af[j0] = (short)f2b(fmaxf(fmaf(scf[kc][j0], lo.f, shf[kc][j0]), 0.f));
        af[j1] = (short)f2b(fmaxf(fmaf(scf[kc][j1], hi.f, shf[kc][j1]), 0.f));
      }
#pragma unroll
      for (int nt = 0; nt < 4; ++nt)
        acc[rt][nt] = __builtin_amdgcn_mfma_f32_16x16x32_bf16(
            af, bfrag[nt][kc], acc[rt][nt], 0, 0, 0);
    }
  }

  // ---- chunk 1 loads (overlap with chunk 0 epilogue) ----
  const int rb1 = rb0 + 256;
#pragma unroll
  for (int rt = 0; rt < 4; ++rt) {
    int row = rb1 + rt * 16 + nn;
    int rowc = row < M ? row : M - 1;
#pragma unroll
    for (int kc = 0; kc < 2; ++kc)
      raw[rt][kc] = *(const uint4*)&A0[(size_t)rowc * 64 + kc * 32 + kq * 8];
  }

  // ---- chunk 0 epilogue ----
#pragma unroll
  for (int rt = 0; rt < 4; ++rt)
#pragma unroll
    for (int nt = 0; nt < 4; ++nt) {
      int col = nt * 16 + nn;
#pragma unroll
      for (int reg = 0; reg < 4; ++reg) {
        int row = rb0 + rt * 16 + kq * 4 + reg;
        if (row < M) {
          float y = acc[rt][nt][reg] + bcol[nt];
          outp[(size_t)row * 64 + col] = f2b(y);
          s[nt] += y; s2[nt] += y * y;
        }
      }
    }

  // ---- chunk 1 compute ----
#pragma unroll
  for (int rt = 0; rt < 4; ++rt)
#pragma unroll
    for (int nt = 0; nt < 4; ++nt) acc[rt][nt] = (f32x4){0.f, 0.f, 0.f, 0.f};
#pragma unroll
  for (int rt = 0; rt < 4; ++rt) {
#pragma unroll
    for (int kc = 0; kc < 2; ++kc) {
      unsigned wbits[4] = {raw[rt][kc].x, raw[rt][kc].y, raw[rt][kc].z, raw[rt][kc].w};
      s16x8 af;
#pragma unroll
      for (int d = 0; d < 4; ++d) {
        union { unsigned u; float f; } lo, hi;
        lo.u = (wbits[d] & 0xffffu) << 16;
        hi.u = wbits[d] & 0xffff0000u;
        int j0 = d * 2, j1 = d * 2 + 1;
        af[j0] = (short)f2b(fmaxf(fmaf(scf[kc][j0], lo.f, shf[kc][j0]), 0.f));
        af[j1] = (short)f2b(fmaxf(fmaf(scf[kc][j1], hi.f, shf[kc][j1]), 0.f));
      }
#pragma unroll
      for (int nt = 0; nt < 4; ++nt)
        acc[rt][nt] = __builtin_amdgcn_mfma_f32_16x16x32_bf16(
            af, bfrag[nt][kc], acc[rt][nt], 0, 0, 0);
    }
  }

  // ---- chunk 1 epilogue ----
#pragma unroll
  for (int rt = 0; rt < 4; ++rt)
#pragma unroll
    for (int nt = 0; nt < 4; ++nt) {
      int col = nt * 16 + nn;
#pragma unroll
      for (int reg = 0; reg < 4; ++reg) {
        int row = rb1 + rt * 16 + kq * 4 + reg;
        if (row < M) {
          float y = acc[rt][nt][reg] + bcol[nt];
          outp[(size_t)row * 64 + col] = f2b(y);
          s[nt] += y; s2[nt] += y * y;
        }
      }
    }

  // ---- stats reduction (once per block) ----
#pragma unroll
  for (int nt = 0; nt < 4; ++nt) {
    s[nt] += __shfl_xor(s[nt], 16, 64);
    s[nt] += __shfl_xor(s[nt], 32, 64);
    s2[nt] += __shfl_xor(s2[nt], 16, 64);
    s2[nt] += __shfl_xor(s2[nt], 32, 64);
  }
  if (tid < 128) red_s[tid] = 0.f;
  __syncthreads();
  if (lane < 16) {
#pragma unroll
    for (int nt = 0; nt < 4; ++nt) {
      atomicAdd(&red_s[nt * 16 + nn], s[nt]);
      atomicAdd(&red_s[64 + nt * 16 + nn], s2[nt]);
    }
  }
  __syncthreads();
  if (tid < 128)
    atomicAdd(&outStats[(blockIdx.x & (NSHARD - 1)) * 128 + tid], red_s[tid]);
}

// ---------------------------------------------------------------------------
// aggr_concat_mfma: fused aggregate + gemm_concat.
// Per 32-node tile: (1) aggr rows = sum relu(bn_st1(t2[CSR range])) built in
// LDS (bf16, stride 72); (2) barrier; (3) u1 = [h|aggr]@W + b, stats(st2).
// Wave w owns output columns [w*16, w*16+16) and aggregates nodes
// [w*8, w*8+8) of the tile. CSR slabs are contiguous per tile.
// ---------------------------------------------------------------------------
__global__ __launch_bounds__(256) void aggr_concat_mfma(
    const unsigned short* __restrict__ t2,   // NE x 64 bf16
    const int* __restrict__ rowptr,
    const float* __restrict__ st1, const float* __restrict__ g1,
    const float* __restrict__ be1, float invE,
    const float* __restrict__ A0,            // h fp32
    const float* __restrict__ W,             // 128 x 64
    const float* __restrict__ bias,
    unsigned short* __restrict__ outp,       // u1 bf16
    float* __restrict__ outStats,            // st2
    int M)
{
  __shared__ __align__(16) unsigned short aggr_s[32 * 72];
  __shared__ float sc_s[64], sh_s[64];
  __shared__ float red_s[128];

  const int tid = threadIdx.x;
  const int lane = tid & 63;
  const int wave = tid >> 6;
  const int nn = lane & 15;
  const int kq = lane >> 4;

  if (tid < 64) {
    float sc, sh;
    bn_coeff(st1, g1, be1, invE, tid, sc, sh);
    sc_s[tid] = sc;
    sh_s[tid] = sh;
  }
  __syncthreads();

  const int rbase = blockIdx.x * 32;

  // ---- phase 1: aggregation into LDS (proven aggregate pattern) ----
  {
    const int c8 = (lane & 7) * 8;
    const int rq = lane >> 3;
    float sc[8], sh[8];
#pragma unroll
    for (int j = 0; j < 8; ++j) { sc[j] = sc_s[c8 + j]; sh[j] = sh_s[c8 + j]; }

    for (int t = 0; t < 8; ++t) {
      int nrow = wave * 8 + t;
      int node = rbase + nrow;
      int lo = 0, hi = 0;
      if (node < NN) { lo = rowptr[node]; hi = rowptr[node + 1]; }
      float acc[8] = {0.f, 0.f, 0.f, 0.f, 0.f, 0.f, 0.f, 0.f};
      for (int i = lo; i < hi; i += 16) {
        int r0 = i + rq;
        int r1 = i + 8 + rq;
        bool h0 = r0 < hi, h1 = r1 < hi;
        uint4 v0 = make_uint4(0u, 0u, 0u, 0u), v1 = make_uint4(0u, 0u, 0u, 0u);
        if (h0) v0 = *(const uint4*)&t2[(size_t)r0 * 64 + c8];
        if (h1) v1 = *(const uint4*)&t2[(size_t)r1 * 64 + c8];
        if (h0) {
          const unsigned w[4] = {v0.x, v0.y, v0.z, v0.w};
#pragma unroll
          for (int d = 0; d < 4; ++d) {
            union { unsigned u; float f; } a0, a1;
            a0.u = (w[d] & 0xffffu) << 16;
            a1.u = w[d] & 0xffff0000u;
            acc[d * 2] += fmaxf(fmaf(sc[d * 2], a0.f, sh[d * 2]), 0.f);
            acc[d * 2 + 1] += fmaxf(fmaf(sc[d * 2 + 1], a1.f, sh[d * 2 + 1]), 0.f);
          }
        }
        if (h1) {
          const unsigned w[4] = {v1.x, v1.y, v1.z, v1.w};
#pragma unroll
          for (int d = 0; d < 4; ++d) {
            union { unsigned u; float f; } a0, a1;
            a0.u = (w[d] & 0xffffu) << 16;
            a1.u = w[d] & 0xffff0000u;
            acc[d * 2] += fmaxf(fmaf(sc[d * 2], a0.f, sh[d * 2]), 0.f);
            acc[d * 2 + 1] += fmaxf(fmaf(sc[d * 2 + 1], a1.f, sh[d * 2 + 1]), 0.f);
          }
        }
      }
#pragma unroll
      for (int j = 0; j < 8; ++j) {
        acc[j] += __shfl_xor(acc[j], 8, 64);
        acc[j] += __shfl_xor(acc[j], 16, 64);
        acc[j] += __shfl_xor(acc[j], 32, 64);
      }
      if (rq == 0) {
        unsigned short o[8];
#pragma unroll
        for (int j = 0; j < 8; ++j) o[j] = f2b(acc[j]);
        *(uint4*)&aggr_s[(size_t)nrow * 72 + c8] = *(const uint4*)o;
      }
    }
  }
  __syncthreads();

  // ---- phase 2: MFMA; wave w -> output cols [w*16, w*16+16) ----
  s16x8 bf[4];  // [kc]
#pragma unroll
  for (int kc = 0; kc < 4; ++kc)
#pragma unroll
    for (int j = 0; j < 8; ++j)
      bf[kc][j] = (short)f2b(W[(kc * 32 + kq * 8 + j) * 64 + wave * 16 + nn]);

  float bcol = bias[wave * 16 + nn];

  f32x4 acc0 = (f32x4){0.f, 0.f, 0.f, 0.f};
  f32x4 acc1 = (f32x4){0.f, 0.f, 0.f, 0.f};
#pragma unroll
  for (int rt = 0; rt < 2; ++rt) {
    int row = rbase + rt * 16 + nn;
    int rowc = row < M ? row : M - 1;
#pragma unroll
    for (int kc = 0; kc < 4; ++kc) {
      s16x8 af;
      if (kc < 2) {
        af = frag_from_f32(&A0[(size_t)rowc * 64 + kc * 32 + kq * 8]);
      } else {
        af = *(const s16x8*)&aggr_s[(size_t)(rt * 16 + nn) * 72 +
                                    (kc - 2) * 32 + kq * 8];
      }
      if (rt == 0)
        acc0 = __builtin_amdgcn_mfma_f32_16x16x32_bf16(af, bf[kc], acc0, 0, 0, 0);
      else
        acc1 = __builtin_amdgcn_mfma_f32_16x16x32_bf16(af, bf[kc], acc1, 0, 0, 0);
    }
  }

  float s = 0.f, s2v = 0.f;
  const int col = wave * 16 + nn;
#pragma unroll
  for (int rt = 0; rt < 2; ++rt) {
    const f32x4 a = rt == 0 ? acc0 : acc1;
#pragma unroll
    for (int reg = 0; reg < 4; ++reg) {
      int row = rbase + rt * 16 + kq * 4 + reg;
      if (row < M) {
        float y = a[reg] + bcol;
        outp[(size_t)row * 64 + col] = f2b(y);
        s += y; s2v += y * y;
      }
    }
  }

  s += __shfl_xor(s, 16, 64);
  s += __shfl_xor(s, 32, 64);
  s2v += __shfl_xor(s2v, 16, 64);
  s2v += __shfl_xor(s2v, 32, 64);
  if (tid < 128) red_s[tid] = 0.f;
  __syncthreads();
  if (lane < 16) {
    atomicAdd(&red_s[wave * 16 + nn], s);
    atomicAdd(&red_s[64 + wave * 16 + nn], s2v);
  }
  __syncthreads();
  if (tid < 128)
    atomicAdd(&outStats[(blockIdx.x & (NSHARD - 1)) * 128 + tid], red_s[tid]);
}

// ---------------------------------------------------------------------------
// pool: partial per-graph column sums with FUSED final residual
// ---------------------------------------------------------------------------
constexpr int POOL_NPB = 128;  // nodes per block

__global__ __launch_bounds__(256) void pool_partial(
    const float* __restrict__ h, const unsigned short* __restrict__ u2,
    const float* __restrict__ st, const float* __restrict__ g,
    const float* __restrict__ be, float invM,
    const int* __restrict__ batch, float* __restrict__ sums)  // NG x 64
{
  __shared__ float sc_s[64], sh_s[64];
  int tid = threadIdx.x;
  if (tid < 64) {
    float sc, sh;
    bn_coeff(st, g, be, invM, tid, sc, sh);
    sc_s[tid] = sc;
    sh_s[tid] = sh;
  }
  __syncthreads();

  int lane = tid & 63;
  int wave = tid >> 6;
  float sc = sc_s[lane], sh = sh_s[lane];
  int base = blockIdx.x * POOL_NPB;
  float acc = 0.f;
  int gcur = -1;
  for (int i = wave; i < POOL_NPB; i += 4) {
    int n = base + i;
    if (n >= NN) break;
    int gb = batch[n];
    if (gb != gcur) {
      if (gcur >= 0) atomicAdd(&sums[gcur * 64 + lane], acc);
      gcur = gb;
      acc = 0.f;
    }
    acc += h[(size_t)n * 64 + lane] +
           fmaxf(fmaf(sc, b2f(u2[(size_t)n * 64 + lane]), sh), 0.f);
  }
  if (gcur >= 0) atomicAdd(&sums[gcur * 64 + lane], acc);
}

DEV int lower_bound_i(const int* __restrict__ a, int n, int v) {
  int lo = 0, hi = n;
  while (lo < hi) {
    int m = (lo + hi) >> 1;
    if (a[m] < v) lo = m + 1; else hi = m;
  }
  return lo;
}

__global__ __launch_bounds__(64) void pool_final(
    const float* __restrict__ sums, const int* __restrict__ batch,
    const float* __restrict__ predW, const float* __restrict__ predB,
    float* __restrict__ out)
{
  int g = blockIdx.x;
  int lane = threadIdx.x;
  int lo = lower_bound_i(batch, NN, g);
  int hi = lower_bound_i(batch, NN, g + 1);
  float cnt = fmaxf((float)(hi - lo), 1.0f);
  float p = sums[g * 64 + lane] / cnt * predW[lane];
#pragma unroll
  for (int off = 32; off > 0; off >>= 1) p += __shfl_down(p, off, 64);
  if (lane == 0) out[g] = p + predB[0];
}

// ---------------------------------------------------------------------------
extern "C" void kernel_launch(void* const* d_in, const int* in_sizes, int n_in,
                              void* d_out, int out_size, void* d_ws, size_t ws_size,
                              hipStream_t stream)
{
  (void)in_sizes; (void)n_in; (void)out_size; (void)ws_size;

  const float* x        = (const float*)d_in[0];
  const float* edge_attr= (const float*)d_in[1];
  const int*   eidx     = (const int*)d_in[2];
  const int*   batch    = (const int*)d_in[3];
  const float* linW     = (const float*)d_in[4];
  const float* linB     = (const float*)d_in[5];
  const float* msgW1    = (const float*)d_in[6];
  const float* msgB1    = (const float*)d_in[7];
  const float* msgG1    = (const float*)d_in[8];
  const float* msgBe1   = (const float*)d_in[9];
  const float* msgW2    = (const float*)d_in[10];
  const float* msgB2    = (const float*)d_in[11];
  const float* msgG2    = (const float*)d_in[12];
  const float* msgBe2   = (const float*)d_in[13];
  const float* updW1    = (const float*)d_in[14];
  const float* updB1    = (const float*)d_in[15];
  const float* updG1    = (const float*)d_in[16];
  const float* updBe1   = (const float*)d_in[17];
  const float* updW2    = (const float*)d_in[18];
  const float* updB2    = (const float*)d_in[19];
  const float* updG2    = (const float*)d_in[20];
  const float* updBe2   = (const float*)d_in[21];
  const float* predW    = (const float*)d_in[22];
  const float* predB    = (const float*)d_in[23];

  const int* srcI = eidx;        // edge_index[0] = source
  const int* dstI = eidx + NE;   // edge_index[1] = target

  char* p = (char*)d_ws;
  float* h  = (float*)p;            p += (size_t)NN * 64 * 4;
  unsigned short* t1 = (unsigned short*)p; p += (size_t)NE * 64 * 2;
  unsigned short* u1 = (unsigned short*)p;   p += (size_t)NN * 64 * 2;
  unsigned short* Hd = (unsigned short*)p;   p += (size_t)NN * 64 * 2;
  unsigned short* Hs = (unsigned short*)p;   p += (size_t)NN * 64 * 2;
  // stats / sums / deg kept contiguous -> single memset
  float* stats = (float*)p;         p += 16 * STB * 4;
  float* sums = (float*)p;          p += NG * 64 * 4;
  int* deg = (int*)p;               p += (size_t)NN * 4;
  int* cursor = (int*)p;            p += (size_t)NN * 4;
  int* rowptr = (int*)p;            p += (size_t)(NN + 1) * 4;
  int* eid = (int*)p;               p += (size_t)NE * 4;
  int* srcP = (int*)p;              p += (size_t)NE * 4;
  int* dstP = (int*)p;              p += (size_t)NE * 4;
  float* eaP = (float*)p;           p += (size_t)NE * 4 * 4;
  int* blockSums = (int*)p;         p += 256 * 4;

  hipMemsetAsync(stats, 0, (size_t)(16 * STB + NG * 64 + NN) * 4, stream);

  hist_lin_kernel<<<(NN * 64 + 255) / 256, 256, 0, stream>>>(
      dstI, deg, x, linW, linB, h);
  scan_pass1<<<SCAN_BLOCKS, 256, 0, stream>>>(deg, blockSums);
  scan_pass3<<<SCAN_BLOCKS, 256, 0, stream>>>(deg, blockSums, rowptr, cursor);
  fill_pos_kernel<<<(NE + 255) / 256, 256, 0, stream>>>(dstI, cursor, eid);
  permute_kernel<<<(NE + 255) / 256, 256, 0, stream>>>(
      eid, srcI, dstI, edge_attr, srcP, dstP, eaP);

  const float invE = 1.0f / (float)NE;
  const float invN = 1.0f / (float)NN;
  const int NB128 = (NN + 127) / 128;         // 391
  const int NB32  = (NN + 31) / 32;           // 1563
  const int NB512 = (NN + 511) / 512;         // 98
  const int EB512 = (NE + 511) / 512;         // 782

  for (int l = 0; l < 4; ++l) {
    float* st0 = stats + (l * 4 + 0) * STB;
    float* st1 = stats + (l * 4 + 1) * STB;
    float* st2 = stats + (l * 4 + 2) * STB;
    float* st3 = stats + (l * 4 + 3) * STB;
    const float* W1 = msgW1 + (size_t)l * 132 * 64;

    // previous layer's residual, fused into the Hd/Hs GEMM
    const unsigned short* prevU2 = (l == 0) ? nullptr : u1;
    const float* pst = (l == 0) ? stats : stats + ((l - 1) * 4 + 3) * STB;
    const float* pg  = (l == 0) ? updG2 : updG2 + (l - 1) * 64;
    const float* pbe = (l == 0) ? updBe2 : updBe2 + (l - 1) * 64;

    // h = h + relu(bn(u2_prev)); Hd = h @ W1[0:64], Hs = h @ W1[64:128]
    gemm_dual_mfma<<<NB128, 256, 0, stream>>>(
        h, W1, prevU2, pst, pg, pbe, invN, Hd, Hs);

    // t1[p] = Hd[dstP] + Hs[srcP] + eaP@W1[128:132] + b1 (bf16) ; stats(st0)
    edge_combine<<<ECB, 256, 0, stream>>>(
        Hd, Hs, eaP, srcP, dstP, W1 + 128 * 64, msgB1 + l * 64,
        t1, st0);

    // t1 = relu(bn(t1)) @ msgW2 + b2 (bf16, in-place, MFMA) ; stats(st1)
    gemm64_bn_mfma<<<EB512, 256, 0, stream>>>(
        t1, msgW2 + (size_t)l * 64 * 64, msgB2 + l * 64,
        st0, msgG1 + l * 64, msgBe1 + l * 64, invE,
        t1, st1, NE);

    // u1 = [h | sum relu(bn(t2)) over CSR] @ updW1 + b1 ; stats(st2)
    aggr_concat_mfma<<<NB32, 256, 0, stream>>>(
        t1, rowptr, st1, msgG2 + l * 64, msgBe2 + l * 64, invE,
        h, updW1 + (size_t)l * 128 * 64, updB1 + l * 64,
        u1, st2, NN);

    // u1 = relu(bn(u1)) @ updW2 + b2 (bf16, in-place, MFMA) ; stats(st3)
    gemm64_bn_mfma<<<NB512, 256, 0, stream>>>(
        u1, updW2 + (size_t)l * 64 * 64, updB2 + l * 64,
        st2, updG1 + l * 64, updBe1 + l * 64, invN,
        u1, st3, NN);
  }

  // final residual (layer 3) fused into pooling
  pool_partial<<<(NN + POOL_NPB - 1) / POOL_NPB, 256, 0, stream>>>(
      h, u1, stats + (3 * 4 + 3) * STB, updG2 + 3 * 64, updBe2 + 3 * 64, invN,
      batch, sums);
  pool_final<<<NG, 64, 0, stream>>>(sums, batch, predW, predB, (float*)d_out);
}

// Round 7
// 624.157 us; speedup vs baseline: 1.0224x; 1.0224x over previous
//
#include <hip/hip_runtime.h>

#define DEV __device__ __forceinline__

constexpr int NN = 50000;   // nodes
constexpr int NE = 400000;  // edges
constexpr int NG = 32;      // graphs
constexpr float EPSV = 1e-5f;
constexpr int SCAN_BLOCKS = 196;  // 196*256 = 50176 >= NN
constexpr int NSHARD = 8;         // stats shards (atomic-contention relief)
constexpr int STB = NSHARD * 128; // floats per BN-stats instance

constexpr int ECB = 2048;               // edge_combine blocks
constexpr int ESLOT = ECB * 256 / 8;    // 65536 edge slots

typedef __attribute__((ext_vector_type(8))) short s16x8;
typedef __attribute__((ext_vector_type(4))) float f32x4;

DEV unsigned short f2b(float f) {  // fp32 -> bf16 RNE (finite inputs)
  union { float f; unsigned u; } x; x.f = f;
  unsigned r = x.u + 0x7fffu + ((x.u >> 16) & 1u);
  return (unsigned short)(r >> 16);
}
DEV float b2f(unsigned short u) {
  union { unsigned u; float f; } x; x.u = ((unsigned)u) << 16; return x.f;
}

DEV s16x8 frag_from_f32(const float* p) {
  const float4 v0 = *(const float4*)p;
  const float4 v1 = *(const float4*)(p + 4);
  s16x8 af;
  af[0] = (short)f2b(v0.x); af[1] = (short)f2b(v0.y);
  af[2] = (short)f2b(v0.z); af[3] = (short)f2b(v0.w);
  af[4] = (short)f2b(v1.x); af[5] = (short)f2b(v1.y);
  af[6] = (short)f2b(v1.z); af[7] = (short)f2b(v1.w);
  return af;
}

DEV void ld8(float* d, const float* p) {
  float4 a = *(const float4*)p;
  float4 b = *(const float4*)(p + 4);
  d[0] = a.x; d[1] = a.y; d[2] = a.z; d[3] = a.w;
  d[4] = b.x; d[5] = b.y; d[6] = b.z; d[7] = b.w;
}

// sum the NSHARD shards of a stats instance and produce scale/shift for ch c.
DEV void bn_coeff(const float* __restrict__ st, const float* __restrict__ g,
                  const float* __restrict__ be, float invM, int c,
                  float& sc, float& sh) {
  float s = 0.f, s2 = 0.f;
#pragma unroll
  for (int k = 0; k < NSHARD; ++k) {
    s += st[k * 128 + c];
    s2 += st[k * 128 + 64 + c];
  }
  float mean = s * invM;
  float var = s2 * invM - mean * mean;
  sc = g[c] * rsqrtf(var + EPSV);
  sh = be[c] - mean * sc;
}

// ---------------------------------------------------------------------------
// hist + lin_in merged (independent work, one dispatch)
// ---------------------------------------------------------------------------
__global__ __launch_bounds__(256) void hist_lin_kernel(
    const int* __restrict__ dstI, int* __restrict__ deg,
    const float* __restrict__ x, const float* __restrict__ W,
    const float* __restrict__ b, float* __restrict__ h)
{
  int gid = blockIdx.x * 256 + threadIdx.x;
  if (gid < NE) atomicAdd(&deg[dstI[gid]], 1);
  if (gid < NN * 64) {
    int n = gid >> 6, c = gid & 63;
    float acc = b[c];
#pragma unroll
    for (int k = 0; k < 11; ++k)
      acc = fmaf(x[n * 11 + k], W[k * 64 + c], acc);
    h[gid] = acc;
  }
}

// ---------------------------------------------------------------------------
// CSR build: scan_pass1 -> scan_pass3 (pass2 folded in) -> fill_pos -> permute
// ---------------------------------------------------------------------------
__global__ __launch_bounds__(256) void scan_pass1(
    const int* __restrict__ deg, int* __restrict__ blockSums)
{
  __shared__ int red[4];
  int tid = threadIdx.x;
  int idx = blockIdx.x * 256 + tid;
  int v = (idx < NN) ? deg[idx] : 0;
#pragma unroll
  for (int off = 32; off > 0; off >>= 1) v += __shfl_down(v, off, 64);
  if ((tid & 63) == 0) red[tid >> 6] = v;
  __syncthreads();
  if (tid == 0) blockSums[blockIdx.x] = red[0] + red[1] + red[2] + red[3];
}

__global__ __launch_bounds__(256) void scan_pass3(
    const int* __restrict__ deg, const int* __restrict__ blockSums,
    int* __restrict__ rowptr, int* __restrict__ cursor)
{
  __shared__ int part[256];
  __shared__ int bsum[256];
  int tid = threadIdx.x;

  // redundant per-block scan of the 196 block sums (replaces scan_pass2)
  bsum[tid] = (tid < SCAN_BLOCKS) ? blockSums[tid] : 0;
  __syncthreads();
  for (int off = 1; off < 256; off <<= 1) {
    int t = 0;
    if (tid >= off) t = bsum[tid - off];
    __syncthreads();
    if (tid >= off) bsum[tid] += t;
    __syncthreads();
  }
  int blockOff = (blockIdx.x == 0) ? 0 : bsum[blockIdx.x - 1];

  int idx = blockIdx.x * 256 + tid;
  int v = (idx < NN) ? deg[idx] : 0;
  part[tid] = v;
  __syncthreads();
  for (int off = 1; off < 256; off <<= 1) {
    int t = 0;
    if (tid >= off) t = part[tid - off];
    __syncthreads();
    if (tid >= off) part[tid] += t;
    __syncthreads();
  }
  int excl = (tid == 0) ? 0 : part[tid - 1];
  int val = blockOff + excl;
  if (idx < NN) { rowptr[idx] = val; cursor[idx] = val; }
  if (idx == 0) rowptr[NN] = NE;
}

__global__ __launch_bounds__(256) void fill_pos_kernel(
    const int* __restrict__ dstI, int* __restrict__ cursor,
    int* __restrict__ eid)
{
  int e = blockIdx.x * 256 + threadIdx.x;
  if (e < NE) {
    int pos = atomicAdd(&cursor[dstI[e]], 1);
    eid[pos] = e;
  }
}

__global__ __launch_bounds__(256) void permute_kernel(
    const int* __restrict__ eid, const int* __restrict__ srcI,
    const int* __restrict__ dstI, const float* __restrict__ ea,
    int* __restrict__ srcP, int* __restrict__ dstP,
    float* __restrict__ eaP)
{
  int p = blockIdx.x * 256 + threadIdx.x;
  if (p < NE) {
    int e = eid[p];
    srcP[p] = srcI[e];
    dstP[p] = dstI[e];
    *(float4*)&eaP[(size_t)p * 4] = *(const float4*)&ea[(size_t)e * 4];
  }
}

// ---------------------------------------------------------------------------
// gemm_dual_mfma: Hd = hn @ W[0:64], Hs = hn @ W[64:128] (bf16 out, MFMA)
// where hn = (u2 ? h + relu(bn(u2)) : h) — fused residual of PREVIOUS layer;
// hn is written back to h (fp32) for gemm_concat / pool.
// ---------------------------------------------------------------------------
__global__ __launch_bounds__(256) void gemm_dual_mfma(
    float* __restrict__ h, const float* __restrict__ W, // 132x64
    const unsigned short* __restrict__ u2,              // may be null (layer 0)
    const float* __restrict__ st, const float* __restrict__ g,
    const float* __restrict__ be, float invM,
    unsigned short* __restrict__ Hd, unsigned short* __restrict__ Hs)
{
  __shared__ __align__(16) unsigned short Wt_s[2 * 64 * 72];  // [half][n][k]
  __shared__ float sc_s[64], sh_s[64];

  const int tid = threadIdx.x;
  const int lane = tid & 63;
  const int wave = tid >> 6;
  const int nn = lane & 15;
  const int kq = lane >> 4;

  if (u2 != nullptr && tid < 64) {
    float sc, sh;
    bn_coeff(st, g, be, invM, tid, sc, sh);
    sc_s[tid] = sc;
    sh_s[tid] = sh;
  }
#pragma unroll
  for (int i = 0; i < 32; ++i) {
    int idx = i * 256 + tid;          // 8192 = 2*64*64
    int half = idx >> 12;
    int rem = idx & 4095;
    int k = rem >> 6, n = rem & 63;
    Wt_s[half * 4608 + n * 72 + k] = f2b(W[idx]);
  }
  __syncthreads();

  s16x8 bfrag[2][4][2];  // [out][nt][kc]
#pragma unroll
  for (int o = 0; o < 2; ++o)
#pragma unroll
    for (int nt = 0; nt < 4; ++nt)
#pragma unroll
      for (int kc = 0; kc < 2; ++kc) {
        const unsigned short* p =
            &Wt_s[o * 4608 + (nt * 16 + nn) * 72 + kc * 32 + kq * 8];
#pragma unroll
        for (int j = 0; j < 8; ++j) bfrag[o][nt][kc][j] = (short)p[j];
      }

  const int rbase = blockIdx.x * 128 + wave * 32;

  f32x4 acc[2][2][4];  // [out][rt][nt]
#pragma unroll
  for (int o = 0; o < 2; ++o)
#pragma unroll
    for (int rt = 0; rt < 2; ++rt)
#pragma unroll
      for (int nt = 0; nt < 4; ++nt) acc[o][rt][nt] = (f32x4){0.f, 0.f, 0.f, 0.f};

#pragma unroll
  for (int rt = 0; rt < 2; ++rt) {
    int row = rbase + rt * 16 + nn;
    int rowc = row < NN ? row : NN - 1;
#pragma unroll
    for (int kc = 0; kc < 2; ++kc) {
      const int c0k = kc * 32 + kq * 8;
      s16x8 af;
      if (u2 != nullptr) {
        float* hp = &h[(size_t)rowc * 64 + c0k];
        float hv[8];
        ld8(hv, hp);
        uint4 uv = *(const uint4*)&u2[(size_t)rowc * 64 + c0k];
        const unsigned uw[4] = {uv.x, uv.y, uv.z, uv.w};
#pragma unroll
        for (int d = 0; d < 4; ++d) {
          union { unsigned u; float f; } lo, hi;
          lo.u = (uw[d] & 0xffffu) << 16;
          hi.u = uw[d] & 0xffff0000u;
          int j0 = d * 2, j1 = d * 2 + 1;
          hv[j0] += fmaxf(fmaf(sc_s[c0k + j0], lo.f, sh_s[c0k + j0]), 0.f);
          hv[j1] += fmaxf(fmaf(sc_s[c0k + j1], hi.f, sh_s[c0k + j1]), 0.f);
        }
        if (row < NN) {
          *(float4*)hp = make_float4(hv[0], hv[1], hv[2], hv[3]);
          *(float4*)(hp + 4) = make_float4(hv[4], hv[5], hv[6], hv[7]);
        }
#pragma unroll
        for (int j = 0; j < 8; ++j) af[j] = (short)f2b(hv[j]);
      } else {
        af = frag_from_f32(&h[(size_t)rowc * 64 + c0k]);
      }
#pragma unroll
      for (int o = 0; o < 2; ++o)
#pragma unroll
        for (int nt = 0; nt < 4; ++nt)
          acc[o][rt][nt] = __builtin_amdgcn_mfma_f32_16x16x32_bf16(
              af, bfrag[o][nt][kc], acc[o][rt][nt], 0, 0, 0);
    }
  }

#pragma unroll
  for (int rt = 0; rt < 2; ++rt)
#pragma unroll
    for (int nt = 0; nt < 4; ++nt) {
      int col = nt * 16 + nn;
#pragma unroll
      for (int reg = 0; reg < 4; ++reg) {
        int row = rbase + rt * 16 + kq * 4 + reg;
        if (row < NN) {
          Hd[(size_t)row * 64 + col] = f2b(acc[0][rt][nt][reg]);
          Hs[(size_t)row * 64 + col] = f2b(acc[1][rt][nt][reg]);
        }
      }
    }
}

// ---------------------------------------------------------------------------
// edge_combine: t1[p] = Hd[dstP[p]] + Hs[srcP[p]] + eaP[p]@Wb + b (bf16 out)
// + stats(st0). 8 lanes/edge, fully-unrolled dual-batch pipeline (R5).
// ---------------------------------------------------------------------------
__global__ __launch_bounds__(256) void edge_combine(
    const unsigned short* __restrict__ Hd, const unsigned short* __restrict__ Hs,
    const float* __restrict__ eaP, const int* __restrict__ srcP,
    const int* __restrict__ dstP, const float* __restrict__ Wb, // 4x64
    const float* __restrict__ bias, unsigned short* __restrict__ t1,
    float* __restrict__ outStats)
{
  __shared__ float red_s[128];
  const int tid = threadIdx.x;
  const int c0 = (tid & 7) * 8;
  float bv[8], w0[8], w1[8], w2[8], w3[8];
#pragma unroll
  for (int j = 0; j < 8; ++j) {
    bv[j] = bias[c0 + j];
    w0[j] = Wb[0 * 64 + c0 + j];
    w1[j] = Wb[1 * 64 + c0 + j];
    w2[j] = Wb[2 * 64 + c0 + j];
    w3[j] = Wb[3 * 64 + c0 + j];
  }

  float s[8], s2[8];
#pragma unroll
  for (int j = 0; j < 8; ++j) { s[j] = 0.f; s2[j] = 0.f; }

  const int e0 = (blockIdx.x * 256 + tid) >> 3;  // [0, ESLOT)

  // ---- batch A loads (unconditional) ----
  int eiA[4];
  float4 avA[4];
  uint4 hdA[4], hsA[4];
#pragma unroll
  for (int u = 0; u < 4; ++u) {
    int ec = e0 + u * ESLOT;
    eiA[u] = ec;
    int si = srcP[ec], di = dstP[ec];
    avA[u] = *(const float4*)&eaP[(size_t)ec * 4];
    hdA[u] = *(const uint4*)&Hd[(size_t)di * 64 + c0];
    hsA[u] = *(const uint4*)&Hs[(size_t)si * 64 + c0];
  }

  // ---- batch B loads (masked; invalid lanes clamp to e0, cache-hot) ----
  int eiB[3];
  bool hasB[3];
  float4 avB[3];
  uint4 hdB[3], hsB[3];
#pragma unroll
  for (int u = 0; u < 3; ++u) {
    int ee = e0 + (4 + u) * ESLOT;
    hasB[u] = ee < NE;
    int ec = hasB[u] ? ee : e0;
    eiB[u] = ec;
    int si = srcP[ec], di = dstP[ec];
    avB[u] = *(const float4*)&eaP[(size_t)ec * 4];
    hdB[u] = *(const uint4*)&Hd[(size_t)di * 64 + c0];
    hsB[u] = *(const uint4*)&Hs[(size_t)si * 64 + c0];
  }

  // ---- batch A compute + store ----
#pragma unroll
  for (int u = 0; u < 4; ++u) {
    const unsigned hdw[4] = {hdA[u].x, hdA[u].y, hdA[u].z, hdA[u].w};
    const unsigned hsw[4] = {hsA[u].x, hsA[u].y, hsA[u].z, hsA[u].w};
    const float4 av = avA[u];
    unsigned short ob[8];
#pragma unroll
    for (int d = 0; d < 4; ++d) {
      union { unsigned uu; float f; } a0, a1, b0, b1u;
      a0.uu = (hdw[d] & 0xffffu) << 16; a1.uu = hdw[d] & 0xffff0000u;
      b0.uu = (hsw[d] & 0xffffu) << 16; b1u.uu = hsw[d] & 0xffff0000u;
      int j0 = d * 2, j1 = d * 2 + 1;
      float y0 = a0.f + b0.f + bv[j0] + av.x * w0[j0] + av.y * w1[j0] + av.z * w2[j0] + av.w * w3[j0];
      float y1 = a1.f + b1u.f + bv[j1] + av.x * w0[j1] + av.y * w1[j1] + av.z * w2[j1] + av.w * w3[j1];
      ob[j0] = f2b(y0); ob[j1] = f2b(y1);
      s[j0] += y0; s2[j0] += y0 * y0;
      s[j1] += y1; s2[j1] += y1 * y1;
    }
    *(uint4*)&t1[(size_t)eiA[u] * 64 + c0] = *(const uint4*)ob;
  }

  // ---- batch B compute + store (masked) ----
#pragma unroll
  for (int u = 0; u < 3; ++u) {
    if (!hasB[u]) continue;
    const unsigned hdw[4] = {hdB[u].x, hdB[u].y, hdB[u].z, hdB[u].w};
    const unsigned hsw[4] = {hsB[u].x, hsB[u].y, hsB[u].z, hsB[u].w};
    const float4 av = avB[u];
    unsigned short ob[8];
#pragma unroll
    for (int d = 0; d < 4; ++d) {
      union { unsigned uu; float f; } a0, a1, b0, b1u;
      a0.uu = (hdw[d] & 0xffffu) << 16; a1.uu = hdw[d] & 0xffff0000u;
      b0.uu = (hsw[d] & 0xffffu) << 16; b1u.uu = hsw[d] & 0xffff0000u;
      int j0 = d * 2, j1 = d * 2 + 1;
      float y0 = a0.f + b0.f + bv[j0] + av.x * w0[j0] + av.y * w1[j0] + av.z * w2[j0] + av.w * w3[j0];
      float y1 = a1.f + b1u.f + bv[j1] + av.x * w0[j1] + av.y * w1[j1] + av.z * w2[j1] + av.w * w3[j1];
      ob[j0] = f2b(y0); ob[j1] = f2b(y1);
      s[j0] += y0; s2[j0] += y0 * y0;
      s[j1] += y1; s2[j1] += y1 * y1;
    }
    *(uint4*)&t1[(size_t)eiB[u] * 64 + c0] = *(const uint4*)ob;
  }

#pragma unroll
  for (int j = 0; j < 8; ++j) {
    s[j] += __shfl_xor(s[j], 8, 64);
    s[j] += __shfl_xor(s[j], 16, 64);
    s[j] += __shfl_xor(s[j], 32, 64);
    s2[j] += __shfl_xor(s2[j], 8, 64);
    s2[j] += __shfl_xor(s2[j], 16, 64);
    s2[j] += __shfl_xor(s2[j], 32, 64);
  }
  if (tid < 128) red_s[tid] = 0.f;
  __syncthreads();
  if ((tid & 63) < 8) {
#pragma unroll
    for (int j = 0; j < 8; ++j) {
      atomicAdd(&red_s[c0 + j], s[j]);
      atomicAdd(&red_s[64 + c0 + j], s2[j]);
    }
  }
  __syncthreads();
  if (tid < 128)
    atomicAdd(&outStats[(blockIdx.x & (NSHARD - 1)) * 128 + tid], red_s[tid]);
}

// ---------------------------------------------------------------------------
// gemm64_bn_mfma: out = relu(bn(A)) @ W + b — bf16 in/out, MFMA, in-place ok.
// 512-row block, 2 chunks of 64 rows per wave.
// ---------------------------------------------------------------------------
__global__ __launch_bounds__(256) void gemm64_bn_mfma(
    const unsigned short* A0,         // bf16 M x 64 (may alias outp)
    const float* __restrict__ W,      // 64 x 64 fp32
    const float* __restrict__ bias,
    const float* __restrict__ inStats,
    const float* __restrict__ inG,
    const float* __restrict__ inBe,
    float invM_in,
    unsigned short* outp,             // bf16 M x 64
    float* __restrict__ outStats,
    int M)
{
  __shared__ __align__(16) unsigned short Wt_s[64 * 72];
  __shared__ float scale_s[64];
  __shared__ float shift_s[64];
  __shared__ float red_s[128];

  const int tid = threadIdx.x;
  const int lane = tid & 63;
  const int wave = tid >> 6;
  const int nn = lane & 15;
  const int kq = lane >> 4;

  if (tid < 64) {
    float sc, sh;
    bn_coeff(inStats, inG, inBe, invM_in, tid, sc, sh);
    scale_s[tid] = sc;
    shift_s[tid] = sh;
  }
#pragma unroll
  for (int i = 0; i < 16; ++i) {
    int idx = i * 256 + tid;
    int k = idx >> 6, n = idx & 63;
    Wt_s[n * 72 + k] = f2b(W[idx]);
  }
  __syncthreads();

  s16x8 bfrag[4][2];
#pragma unroll
  for (int nt = 0; nt < 4; ++nt)
#pragma unroll
    for (int kc = 0; kc < 2; ++kc)
      bfrag[nt][kc] = *(const s16x8*)&Wt_s[(nt * 16 + nn) * 72 + kc * 32 + kq * 8];

  float scf[2][8], shf[2][8];
#pragma unroll
  for (int kc = 0; kc < 2; ++kc) {
    int k0 = kc * 32 + kq * 8;
    ld8(scf[kc], &scale_s[k0]);
    ld8(shf[kc], &shift_s[k0]);
  }

  float bcol[4];
#pragma unroll
  for (int nt = 0; nt < 4; ++nt) bcol[nt] = bias[nt * 16 + nn];

  float s[4] = {0.f, 0.f, 0.f, 0.f};
  float s2[4] = {0.f, 0.f, 0.f, 0.f};

  uint4 raw[4][2];
  f32x4 acc[4][4];

  // ---- chunk 0 loads ----
  const int rb0 = blockIdx.x * 512 + wave * 64;
#pragma unroll
  for (int rt = 0; rt < 4; ++rt) {
    int row = rb0 + rt * 16 + nn;
    int rowc = row < M ? row : M - 1;
#pragma unroll
    for (int kc = 0; kc < 2; ++kc)
      raw[rt][kc] = *(const uint4*)&A0[(size_t)rowc * 64 + kc * 32 + kq * 8];
  }

  // ---- chunk 0 compute ----
#pragma unroll
  for (int rt = 0; rt < 4; ++rt)
#pragma unroll
    for (int nt = 0; nt < 4; ++nt) acc[rt][nt] = (f32x4){0.f, 0.f, 0.f, 0.f};
#pragma unroll
  for (int rt = 0; rt < 4; ++rt) {
#pragma unroll
    for (int kc = 0; kc < 2; ++kc) {
      unsigned wbits[4] = {raw[rt][kc].x, raw[rt][kc].y, raw[rt][kc].z, raw[rt][kc].w};
      s16x8 af;
#pragma unroll
      for (int d = 0; d < 4; ++d) {
        union { unsigned u; float f; } lo, hi;
        lo.u = (wbits[d] & 0xffffu) << 16;
        hi.u = wbits[d] & 0xffff0000u;
        int j0 = d * 2, j1 = d * 2 + 1;
        af[j0] = (short)f2b(fmaxf(fmaf(scf[kc][j0], lo.f, shf[kc][j0]), 0.f));
        af[j1] = (short)f2b(fmaxf(fmaf(scf[kc][j1], hi.f, shf[kc][j1]), 0.f));
      }
#pragma unroll
      for (int nt = 0; nt < 4; ++nt)
        acc[rt][nt] = __builtin_amdgcn_mfma_f32_16x16x32_bf16(
            af, bfrag[nt][kc], acc[rt][nt], 0, 0, 0);
    }
  }

  // ---- chunk 1 loads (overlap with chunk 0 epilogue) ----
  const int rb1 = rb0 + 256;
#pragma unroll
  for (int rt = 0; rt < 4; ++rt) {
    int row = rb1 + rt * 16 + nn;
    int rowc = row < M ? row : M - 1;
#pragma unroll
    for (int kc = 0; kc < 2; ++kc)
      raw[rt][kc] = *(const uint4*)&A0[(size_t)rowc * 64 + kc * 32 + kq * 8];
  }

  // ---- chunk 0 epilogue ----
#pragma unroll
  for (int rt = 0; rt < 4; ++rt)
#pragma unroll
    for (int nt = 0; nt < 4; ++nt) {
      int col = nt * 16 + nn;
#pragma unroll
      for (int reg = 0; reg < 4; ++reg) {
        int row = rb0 + rt * 16 + kq * 4 + reg;
        if (row < M) {
          float y = acc[rt][nt][reg] + bcol[nt];
          outp[(size_t)row * 64 + col] = f2b(y);
          s[nt] += y; s2[nt] += y * y;
        }
      }
    }

  // ---- chunk 1 compute ----
#pragma unroll
  for (int rt = 0; rt < 4; ++rt)
#pragma unroll
    for (int nt = 0; nt < 4; ++nt) acc[rt][nt] = (f32x4){0.f, 0.f, 0.f, 0.f};
#pragma unroll
  for (int rt = 0; rt < 4; ++rt) {
#pragma unroll
    for (int kc = 0; kc < 2; ++kc) {
      unsigned wbits[4] = {raw[rt][kc].x, raw[rt][kc].y, raw[rt][kc].z, raw[rt][kc].w};
      s16x8 af;
#pragma unroll
      for (int d = 0; d < 4; ++d) {
        union { unsigned u; float f; } lo, hi;
        lo.u = (wbits[d] & 0xffffu) << 16;
        hi.u = wbits[d] & 0xffff0000u;
        int j0 = d * 2, j1 = d * 2 + 1;
        af[j0] = (short)f2b(fmaxf(fmaf(scf[kc][j0], lo.f, shf[kc][j0]), 0.f));
        af[j1] = (short)f2b(fmaxf(fmaf(scf[kc][j1], hi.f, shf[kc][j1]), 0.f));
      }
#pragma unroll
      for (int nt = 0; nt < 4; ++nt)
        acc[rt][nt] = __builtin_amdgcn_mfma_f32_16x16x32_bf16(
            af, bfrag[nt][kc], acc[rt][nt], 0, 0, 0);
    }
  }

  // ---- chunk 1 epilogue ----
#pragma unroll
  for (int rt = 0; rt < 4; ++rt)
#pragma unroll
    for (int nt = 0; nt < 4; ++nt) {
      int col = nt * 16 + nn;
#pragma unroll
      for (int reg = 0; reg < 4; ++reg) {
        int row = rb1 + rt * 16 + kq * 4 + reg;
        if (row < M) {
          float y = acc[rt][nt][reg] + bcol[nt];
          outp[(size_t)row * 64 + col] = f2b(y);
          s[nt] += y; s2[nt] += y * y;
        }
      }
    }

  // ---- stats reduction (once per block) ----
#pragma unroll
  for (int nt = 0; nt < 4; ++nt) {
    s[nt] += __shfl_xor(s[nt], 16, 64);
    s[nt] += __shfl_xor(s[nt], 32, 64);
    s2[nt] += __shfl_xor(s2[nt], 16, 64);
    s2[nt] += __shfl_xor(s2[nt], 32, 64);
  }
  if (tid < 128) red_s[tid] = 0.f;
  __syncthreads();
  if (lane < 16) {
#pragma unroll
    for (int nt = 0; nt < 4; ++nt) {
      atomicAdd(&red_s[nt * 16 + nn], s[nt]);
      atomicAdd(&red_s[64 + nt * 16 + nn], s2[nt]);
    }
  }
  __syncthreads();
  if (tid < 128)
    atomicAdd(&outStats[(blockIdx.x & (NSHARD - 1)) * 128 + tid], red_s[tid]);
}

// ---------------------------------------------------------------------------
// gemm_concat_mfma: u1 = [h(fp32)|aggr(bf16)] @ W(128x64) + b (bf16 out)
// ---------------------------------------------------------------------------
__global__ __launch_bounds__(256) void gemm_concat_mfma(
    const float* __restrict__ A0,            // h fp32
    const unsigned short* __restrict__ A1b,  // aggr bf16
    const float* __restrict__ W,             // 128 x 64
    const float* __restrict__ bias,
    unsigned short* __restrict__ outp,       // u1 bf16
    float* __restrict__ outStats,
    int M)
{
  __shared__ __align__(16) unsigned short Wt_s[64 * 136];
  __shared__ float red_s[128];

  const int tid = threadIdx.x;
  const int lane = tid & 63;
  const int wave = tid >> 6;
  const int nn = lane & 15;
  const int kq = lane >> 4;

#pragma unroll
  for (int i = 0; i < 32; ++i) {
    int idx = i * 256 + tid;          // 8192
    int k = idx >> 6, n = idx & 63;
    Wt_s[n * 136 + k] = f2b(W[idx]);
  }
  __syncthreads();

  s16x8 bfrag[4][4];  // [nt][kc]
#pragma unroll
  for (int nt = 0; nt < 4; ++nt)
#pragma unroll
    for (int kc = 0; kc < 4; ++kc) {
      const unsigned short* p = &Wt_s[(nt * 16 + nn) * 136 + kc * 32 + kq * 8];
#pragma unroll
      for (int j = 0; j < 8; ++j) bfrag[nt][kc][j] = (short)p[j];
    }

  const int rbase = blockIdx.x * 128 + wave * 32;

  f32x4 acc[2][4];
#pragma unroll
  for (int rt = 0; rt < 2; ++rt)
#pragma unroll
    for (int nt = 0; nt < 4; ++nt) acc[rt][nt] = (f32x4){0.f, 0.f, 0.f, 0.f};

#pragma unroll
  for (int rt = 0; rt < 2; ++rt) {
    int row = rbase + rt * 16 + nn;
    int rowc = row < M ? row : M - 1;
#pragma unroll
    for (int kc = 0; kc < 4; ++kc) {
      s16x8 af;
      if (kc < 2) {
        af = frag_from_f32(&A0[(size_t)rowc * 64 + kc * 32 + kq * 8]);
      } else {
        af = *(const s16x8*)&A1b[(size_t)rowc * 64 + (kc - 2) * 32 + kq * 8];
      }
#pragma unroll
      for (int nt = 0; nt < 4; ++nt)
        acc[rt][nt] = __builtin_amdgcn_mfma_f32_16x16x32_bf16(
            af, bfrag[nt][kc], acc[rt][nt], 0, 0, 0);
    }
  }

  float bcol[4];
#pragma unroll
  for (int nt = 0; nt < 4; ++nt) bcol[nt] = bias[nt * 16 + nn];

  float s[4] = {0.f, 0.f, 0.f, 0.f};
  float s2[4] = {0.f, 0.f, 0.f, 0.f};
#pragma unroll
  for (int rt = 0; rt < 2; ++rt)
#pragma unroll
    for (int nt = 0; nt < 4; ++nt) {
      int col = nt * 16 + nn;
#pragma unroll
      for (int reg = 0; reg < 4; ++reg) {
        int row = rbase + rt * 16 + kq * 4 + reg;
        if (row < M) {
          float y = acc[rt][nt][reg] + bcol[nt];
          outp[(size_t)row * 64 + col] = f2b(y);
          s[nt] += y; s2[nt] += y * y;
        }
      }
    }
#pragma unroll
  for (int nt = 0; nt < 4; ++nt) {
    s[nt] += __shfl_xor(s[nt], 16, 64);
    s[nt] += __shfl_xor(s[nt], 32, 64);
    s2[nt] += __shfl_xor(s2[nt], 16, 64);
    s2[nt] += __shfl_xor(s2[nt], 32, 64);
  }
  if (tid < 128) red_s[tid] = 0.f;
  __syncthreads();
  if (lane < 16) {
#pragma unroll
    for (int nt = 0; nt < 4; ++nt) {
      atomicAdd(&red_s[nt * 16 + nn], s[nt]);
      atomicAdd(&red_s[64 + nt * 16 + nn], s2[nt]);
    }
  }
  __syncthreads();
  if (tid < 128)
    atomicAdd(&outStats[(blockIdx.x & (NSHARD - 1)) * 128 + tid], red_s[tid]);
}

// ---------------------------------------------------------------------------
// aggregate (wide): lane = (8 channels)x(row-octet). uint4 loads.
// ---------------------------------------------------------------------------
__global__ __launch_bounds__(256) void aggregate_kernel(
    const unsigned short* __restrict__ t2, const int* __restrict__ rowptr,
    const float* __restrict__ stats, const float* __restrict__ g,
    const float* __restrict__ be, float invM,
    unsigned short* __restrict__ aggr)
{
  __shared__ float sc_s[64], sh_s[64];
  const int tid = threadIdx.x;
  if (tid < 64) {
    float sc, sh;
    bn_coeff(stats, g, be, invM, tid, sc, sh);
    sc_s[tid] = sc;
    sh_s[tid] = sh;
  }
  __syncthreads();

  int node = (blockIdx.x * 256 + tid) >> 6;
  int lane = tid & 63;
  if (node >= NN) return;
  const int c8 = (lane & 7) * 8;    // this lane's 8 channels
  const int rq = lane >> 3;         // row offset within octet (0..7)

  float sc[8], sh[8];
#pragma unroll
  for (int j = 0; j < 8; ++j) {
    sc[j] = sc_s[c8 + j];
    sh[j] = sh_s[c8 + j];
  }

  int lo = rowptr[node], hi = rowptr[node + 1];
  float acc[8] = {0.f, 0.f, 0.f, 0.f, 0.f, 0.f, 0.f, 0.f};

  for (int i = lo; i < hi; i += 16) {
    int r0 = i + rq;
    int r1 = i + 8 + rq;
    bool h0 = r0 < hi, h1 = r1 < hi;
    uint4 v0 = make_uint4(0u, 0u, 0u, 0u), v1 = make_uint4(0u, 0u, 0u, 0u);
    if (h0) v0 = *(const uint4*)&t2[(size_t)r0 * 64 + c8];
    if (h1) v1 = *(const uint4*)&t2[(size_t)r1 * 64 + c8];
    if (h0) {
      const unsigned w[4] = {v0.x, v0.y, v0.z, v0.w};
#pragma unroll
      for (int d = 0; d < 4; ++d) {
        union { unsigned u; float f; } a0, a1;
        a0.u = (w[d] & 0xffffu) << 16;
        a1.u = w[d] & 0xffff0000u;
        acc[d * 2] += fmaxf(fmaf(sc[d * 2], a0.f, sh[d * 2]), 0.f);
        acc[d * 2 + 1] += fmaxf(fmaf(sc[d * 2 + 1], a1.f, sh[d * 2 + 1]), 0.f);
      }
    }
    if (h1) {
      const unsigned w[4] = {v1.x, v1.y, v1.z, v1.w};
#pragma unroll
      for (int d = 0; d < 4; ++d) {
        union { unsigned u; float f; } a0, a1;
        a0.u = (w[d] & 0xffffu) << 16;
        a1.u = w[d] & 0xffff0000u;
        acc[d * 2] += fmaxf(fmaf(sc[d * 2], a0.f, sh[d * 2]), 0.f);
        acc[d * 2 + 1] += fmaxf(fmaf(sc[d * 2 + 1], a1.f, sh[d * 2 + 1]), 0.f);
      }
    }
  }
#pragma unroll
  for (int j = 0; j < 8; ++j) {
    acc[j] += __shfl_xor(acc[j], 8, 64);
    acc[j] += __shfl_xor(acc[j], 16, 64);
    acc[j] += __shfl_xor(acc[j], 32, 64);
  }
  if (rq == 0) {
    unsigned short o[8];
#pragma unroll
    for (int j = 0; j < 8; ++j) o[j] = f2b(acc[j]);
    *(uint4*)&aggr[(size_t)node * 64 + c8] = *(const uint4*)o;
  }
}

// ---------------------------------------------------------------------------
// pool: partial per-graph column sums with FUSED final residual
// ---------------------------------------------------------------------------
constexpr int POOL_NPB = 128;  // nodes per block

__global__ __launch_bounds__(256) void pool_partial(
    const float* __restrict__ h, const unsigned short* __restrict__ u2,
    const float* __restrict__ st, const float* __restrict__ g,
    const float* __restrict__ be, float invM,
    const int* __restrict__ batch, float* __restrict__ sums)  // NG x 64
{
  __shared__ float sc_s[64], sh_s[64];
  int tid = threadIdx.x;
  if (tid < 64) {
    float sc, sh;
    bn_coeff(st, g, be, invM, tid, sc, sh);
    sc_s[tid] = sc;
    sh_s[tid] = sh;
  }
  __syncthreads();

  int lane = tid & 63;
  int wave = tid >> 6;
  float sc = sc_s[lane], sh = sh_s[lane];
  int base = blockIdx.x * POOL_NPB;
  float acc = 0.f;
  int gcur = -1;
  for (int i = wave; i < POOL_NPB; i += 4) {
    int n = base + i;
    if (n >= NN) break;
    int gb = batch[n];
    if (gb != gcur) {
      if (gcur >= 0) atomicAdd(&sums[gcur * 64 + lane], acc);
      gcur = gb;
      acc = 0.f;
    }
    acc += h[(size_t)n * 64 + lane] +
           fmaxf(fmaf(sc, b2f(u2[(size_t)n * 64 + lane]), sh), 0.f);
  }
  if (gcur >= 0) atomicAdd(&sums[gcur * 64 + lane], acc);
}

DEV int lower_bound_i(const int* __restrict__ a, int n, int v) {
  int lo = 0, hi = n;
  while (lo < hi) {
    int m = (lo + hi) >> 1;
    if (a[m] < v) lo = m + 1; else hi = m;
  }
  return lo;
}

__global__ __launch_bounds__(64) void pool_final(
    const float* __restrict__ sums, const int* __restrict__ batch,
    const float* __restrict__ predW, const float* __restrict__ predB,
    float* __restrict__ out)
{
  int g = blockIdx.x;
  int lane = threadIdx.x;
  int lo = lower_bound_i(batch, NN, g);
  int hi = lower_bound_i(batch, NN, g + 1);
  float cnt = fmaxf((float)(hi - lo), 1.0f);
  float p = sums[g * 64 + lane] / cnt * predW[lane];
#pragma unroll
  for (int off = 32; off > 0; off >>= 1) p += __shfl_down(p, off, 64);
  if (lane == 0) out[g] = p + predB[0];
}

// ---------------------------------------------------------------------------
extern "C" void kernel_launch(void* const* d_in, const int* in_sizes, int n_in,
                              void* d_out, int out_size, void* d_ws, size_t ws_size,
                              hipStream_t stream)
{
  (void)in_sizes; (void)n_in; (void)out_size; (void)ws_size;

  const float* x        = (const float*)d_in[0];
  const float* edge_attr= (const float*)d_in[1];
  const int*   eidx     = (const int*)d_in[2];
  const int*   batch    = (const int*)d_in[3];
  const float* linW     = (const float*)d_in[4];
  const float* linB     = (const float*)d_in[5];
  const float* msgW1    = (const float*)d_in[6];
  const float* msgB1    = (const float*)d_in[7];
  const float* msgG1    = (const float*)d_in[8];
  const float* msgBe1   = (const float*)d_in[9];
  const float* msgW2    = (const float*)d_in[10];
  const float* msgB2    = (const float*)d_in[11];
  const float* msgG2    = (const float*)d_in[12];
  const float* msgBe2   = (const float*)d_in[13];
  const float* updW1    = (const float*)d_in[14];
  const float* updB1    = (const float*)d_in[15];
  const float* updG1    = (const float*)d_in[16];
  const float* updBe1   = (const float*)d_in[17];
  const float* updW2    = (const float*)d_in[18];
  const float* updB2    = (const float*)d_in[19];
  const float* updG2    = (const float*)d_in[20];
  const float* updBe2   = (const float*)d_in[21];
  const float* predW    = (const float*)d_in[22];
  const float* predB    = (const float*)d_in[23];

  const int* srcI = eidx;        // edge_index[0] = source
  const int* dstI = eidx + NE;   // edge_index[1] = target

  char* p = (char*)d_ws;
  float* h  = (float*)p;            p += (size_t)NN * 64 * 4;
  unsigned short* t1 = (unsigned short*)p; p += (size_t)NE * 64 * 2;
  unsigned short* aggr = (unsigned short*)p; p += (size_t)NN * 64 * 2;
  unsigned short* u1 = (unsigned short*)p;   p += (size_t)NN * 64 * 2;
  unsigned short* Hd = (unsigned short*)p;   p += (size_t)NN * 64 * 2;
  unsigned short* Hs = (unsigned short*)p;   p += (size_t)NN * 64 * 2;
  // stats / sums / deg kept contiguous -> single memset
  float* stats = (float*)p;         p += 16 * STB * 4;
  float* sums = (float*)p;          p += NG * 64 * 4;
  int* deg = (int*)p;               p += (size_t)NN * 4;
  int* cursor = (int*)p;            p += (size_t)NN * 4;
  int* rowptr = (int*)p;            p += (size_t)(NN + 1) * 4;
  int* eid = (int*)p;               p += (size_t)NE * 4;
  int* srcP = (int*)p;              p += (size_t)NE * 4;
  int* dstP = (int*)p;              p += (size_t)NE * 4;
  float* eaP = (float*)p;           p += (size_t)NE * 4 * 4;
  int* blockSums = (int*)p;         p += 256 * 4;

  hipMemsetAsync(stats, 0, (size_t)(16 * STB + NG * 64 + NN) * 4, stream);

  hist_lin_kernel<<<(NN * 64 + 255) / 256, 256, 0, stream>>>(
      dstI, deg, x, linW, linB, h);
  scan_pass1<<<SCAN_BLOCKS, 256, 0, stream>>>(deg, blockSums);
  scan_pass3<<<SCAN_BLOCKS, 256, 0, stream>>>(deg, blockSums, rowptr, cursor);
  fill_pos_kernel<<<(NE + 255) / 256, 256, 0, stream>>>(dstI, cursor, eid);
  permute_kernel<<<(NE + 255) / 256, 256, 0, stream>>>(
      eid, srcI, dstI, edge_attr, srcP, dstP, eaP);

  const float invE = 1.0f / (float)NE;
  const float invN = 1.0f / (float)NN;
  const int NB128 = (NN + 127) / 128;         // 391
  const int NB512 = (NN + 511) / 512;         // 98
  const int EB512 = (NE + 511) / 512;         // 782

  for (int l = 0; l < 4; ++l) {
    float* st0 = stats + (l * 4 + 0) * STB;
    float* st1 = stats + (l * 4 + 1) * STB;
    float* st2 = stats + (l * 4 + 2) * STB;
    float* st3 = stats + (l * 4 + 3) * STB;
    const float* W1 = msgW1 + (size_t)l * 132 * 64;

    // previous layer's residual, fused into the Hd/Hs GEMM
    const unsigned short* prevU2 = (l == 0) ? nullptr : u1;
    const float* pst = (l == 0) ? stats : stats + ((l - 1) * 4 + 3) * STB;
    const float* pg  = (l == 0) ? updG2 : updG2 + (l - 1) * 64;
    const float* pbe = (l == 0) ? updBe2 : updBe2 + (l - 1) * 64;

    // h = h + relu(bn(u2_prev)); Hd = h @ W1[0:64], Hs = h @ W1[64:128]
    gemm_dual_mfma<<<NB128, 256, 0, stream>>>(
        h, W1, prevU2, pst, pg, pbe, invN, Hd, Hs);

    // t1[p] = Hd[dstP] + Hs[srcP] + eaP@W1[128:132] + b1 (bf16) ; stats(st0)
    edge_combine<<<ECB, 256, 0, stream>>>(
        Hd, Hs, eaP, srcP, dstP, W1 + 128 * 64, msgB1 + l * 64,
        t1, st0);

    // t1 = relu(bn(t1)) @ msgW2 + b2 (bf16, in-place, MFMA) ; stats(st1)
    gemm64_bn_mfma<<<EB512, 256, 0, stream>>>(
        t1, msgW2 + (size_t)l * 64 * 64, msgB2 + l * 64,
        st0, msgG1 + l * 64, msgBe1 + l * 64, invE,
        t1, st1, NE);

    // aggr[n] = sum relu(bn(t2)) over CSR rows (wide sequential stream)
    aggregate_kernel<<<(NN * 64 + 255) / 256, 256, 0, stream>>>(
        t1, rowptr, st1, msgG2 + l * 64, msgBe2 + l * 64, invE, aggr);

    // u1 = [h|aggr] @ updW1 + b1 (MFMA, bf16 out) ; stats(st2)
    gemm_concat_mfma<<<NB128, 256, 0, stream>>>(
        h, aggr, updW1 + (size_t)l * 128 * 64, updB1 + l * 64,
        u1, st2, NN);

    // u1 = relu(bn(u1)) @ updW2 + b2 (bf16, in-place, MFMA) ; stats(st3)
    gemm64_bn_mfma<<<NB512, 256, 0, stream>>>(
        u1, updW2 + (size_t)l * 64 * 64, updB2 + l * 64,
        st2, updG1 + l * 64, updBe1 + l * 64, invN,
        u1, st3, NN);
  }

  // final residual (layer 3) fused into pooling
  pool_partial<<<(NN + POOL_NPB - 1) / POOL_NPB, 256, 0, stream>>>(
      h, u1, stats + (3 * 4 + 3) * STB, updG2 + 3 * 64, updBe2 + 3 * 64, invN,
      batch, sums);
  pool_final<<<NG, 64, 0, stream>>>(sums, batch, predW, predB, (float*)d_out);
}